// Round 10
// baseline (400.869 us; speedup 1.0000x reference)
//
#include <hip/hip_runtime.h>

// AutoInt fused: embedding gather -> 2x MHSA (32 fields, 4 heads x 32) -> logit.
// One block (256 thr, 4 waves) per sample; wave h = head h.
// R10 = R9 + cooperative per-projection weight staging into LDS (XOR-swizzled
//     to avoid the 32-way stride conflict). Converts ~48 scattered 200-600cyc
//     L2 loads per wave-layer into coalesced block staging + LDS reads.

#define NSAMP 8192
#define S_Y1 72    // layer1 input stride (shorts): 144B rows (16B-aligned)
#define S_Y2 136   // layer2 input stride (shorts): 272B rows (16B-aligned)
#define S_T 36     // 32x32 tile stride (shorts): 72B rows

typedef __attribute__((ext_vector_type(8))) short bf8_t;   // 8 bf16 (4 VGPRs)
typedef __attribute__((ext_vector_type(16))) float f16v;   // 32x32 C/D

__device__ __forceinline__ short f2bf(float f) {
  unsigned u = __float_as_uint(f);
  u += 0x7fffu + ((u >> 16) & 1u);   // RNE
  return (short)(u >> 16);
}
__device__ __forceinline__ unsigned pack2(float a, float b) {
  return ((unsigned)(unsigned short)f2bf(a)) |
         (((unsigned)(unsigned short)f2bf(b)) << 16);
}
__device__ __forceinline__ float bf2f(short s) {
  return __uint_as_float(((unsigned)(unsigned short)s) << 16);
}
__device__ __forceinline__ f16v mfma32(bf8_t a, bf8_t b, f16v c) {
  return __builtin_amdgcn_mfma_f32_32x32x16_bf16(a, b, c, 0, 0, 0);
}

// Stage full W (128 x D bf16) global -> LDS, XOR-swizzled chunks of 8 shorts:
// dst chunk index = ch ^ (n & (CH-1)). Coalesced dwordx4 both sides.
template<int D>
__device__ __forceinline__ void stageW(const short* __restrict__ Wg,
                                       short* wsh, int t) {
  constexpr int CH = D / 8;            // 16B chunks per row (8 or 16)
  constexpr int ITERS = 128 * CH / 256;
#pragma unroll
  for (int i = 0; i < ITERS; ++i) {
    int q = t + i * 256;
    int n = q / CH, ch = q % CH;
    uint4 v = *(const uint4*)&Wg[n * D + ch * 8];
    *(uint4*)&wsh[n * D + ((ch ^ (n & (CH - 1))) << 3)] = v;
  }
}

// C = y(32xD) * W(32xD)^T + bias, W read from swizzled LDS buffer.
template<int D>
__device__ __forceinline__ f16v proj32(const bf8_t (&af)[D / 16],
                                       const short* wsh,
                                       const float* __restrict__ bias,
                                       int n0, int col, int h2) {
  constexpr int CH = D / 8;
  float bb = bias[n0 + col];
  f16v acc;
#pragma unroll
  for (int i = 0; i < 16; ++i) acc[i] = bb;
  const int n = n0 + col;
#pragma unroll
  for (int kc = 0; kc < D / 16; ++kc) {
    int chunk = kc * 2 + h2;
    bf8_t b = *(const bf8_t*)&wsh[n * D + ((chunk ^ (n & (CH - 1))) << 3)];
    acc = mfma32(af[kc], b, acc);
  }
  return acc;
}

// One attention layer for this wave's head (R9 overlay structure + W staging).
template<int D_IN, int S_IN, bool FUSE>
__device__ float attn_layer(const short* yIn, short* yOut,
                            const short* __restrict__ Wq, const short* __restrict__ Wk,
                            const short* __restrict__ Wv, const short* __restrict__ Wr,
                            const float* __restrict__ bq, const float* __restrict__ bk,
                            const float* __restrict__ bvp, const float* __restrict__ br,
                            short* bQ, short* bK, short* wsh,
                            const short* __restrict__ lwT) {
  constexpr int KS = D_IN / 16;
  const int lane = threadIdx.x & 63;
  const int col = lane & 31;
  const int h2 = lane >> 5;
  const int head = threadIdx.x >> 6;
  const int n0 = head * 32;
  const int t = threadIdx.x;

  // Stage Wq while loading A-fragments (independent; one barrier covers both)
  stageW<D_IN>(Wq, wsh, t);
  bf8_t af[KS];
#pragma unroll
  for (int kc = 0; kc < KS; ++kc)
    af[kc] = *(const bf8_t*)&yIn[col * S_IN + kc * 16 + h2 * 8];
  __syncthreads();   // yIn dead (tiles writable), Wq staged

  // ---- Q -> bQ row-major
  {
    f16v q = proj32<D_IN>(af, wsh, bq, n0, col, h2);
#pragma unroll
    for (int reg = 0; reg < 16; ++reg) {
      int row = (reg & 3) + 8 * (reg >> 2) + 4 * h2;
      bQ[row * S_T + col] = f2bf(q[reg]);
    }
  }
  __syncthreads();   // all waves done reading Wq
  stageW<D_IN>(Wk, wsh, t);
  __syncthreads();

  // ---- K -> bK row-major
  {
    f16v k = proj32<D_IN>(af, wsh, bk, n0, col, h2);
#pragma unroll
    for (int reg = 0; reg < 16; ++reg) {
      int row = (reg & 3) + 8 * (reg >> 2) + 4 * h2;
      bK[row * S_T + col] = f2bf(k[reg]);
    }
  }
  __syncthreads();   // all waves done reading Wk
  stageW<D_IN>(Wr, wsh, t);
  __syncthreads();

  // ---- Res -> registers (C-layout, aligned with PV output)
  f16v res = proj32<D_IN>(af, wsh, br, n0, col, h2);

  // ---- scores = Q K^T (K-dim = 32 head dims -> 2 chunks)
  f16v z;
#pragma unroll
  for (int i = 0; i < 16; ++i) z[i] = 0.f;
#pragma unroll
  for (int kc = 0; kc < 2; ++kc) {
    bf8_t qa = *(const bf8_t*)&bQ[col * S_T + kc * 16 + h2 * 8];
    bf8_t kb = *(const bf8_t*)&bK[col * S_T + kc * 16 + h2 * 8];
    z = mfma32(qa, kb, z);
  }

  // ---- e = exp(z) unnormalized -> bQ (per-head region; no cross-wave hazard)
#pragma unroll
  for (int reg = 0; reg < 16; ++reg) {
    int row = (reg & 3) + 8 * (reg >> 2) + 4 * h2;
    bQ[row * S_T + col] = f2bf(__expf(z[reg]));
  }

  __syncthreads();   // all waves done reading Wr
  stageW<D_IN>(Wv, wsh, t);
  __syncthreads();

  // ---- V -> bK transposed: bK[i=col][f=row], packed short4 runs
  {
    f16v v = proj32<D_IN>(af, wsh, bvp, n0, col, h2);
#pragma unroll
    for (int g = 0; g < 4; ++g) {
      short4 pk;
      pk.x = f2bf(v[g * 4 + 0]); pk.y = f2bf(v[g * 4 + 1]);
      pk.z = f2bf(v[g * 4 + 2]); pk.w = f2bf(v[g * 4 + 3]);
      *(short4*)&bK[col * S_T + 8 * g + 4 * h2] = pk;
    }
  }

  // ---- PV (unnormalized) + row-sums via all-ones B-frag
  const short onebf = (short)0x3F80;
  bf8_t ones = {onebf, onebf, onebf, onebf, onebf, onebf, onebf, onebf};
  f16v pv, sums;
#pragma unroll
  for (int i = 0; i < 16; ++i) { pv[i] = 0.f; sums[i] = 0.f; }
#pragma unroll
  for (int kc = 0; kc < 2; ++kc) {
    bf8_t pa = *(const bf8_t*)&bQ[col * S_T + kc * 16 + h2 * 8];
    bf8_t vb = *(const bf8_t*)&bK[col * S_T + kc * 16 + h2 * 8];
    pv = mfma32(pa, vb, pv);
    sums = mfma32(pa, ones, sums);
  }

  // ---- O = PV/s + Res, relu; store (layer1) or fuse logit dot (layer2)
  float p = 0.f;
  if (FUSE) {
#pragma unroll
    for (int g = 0; g < 4; ++g) {
      short4 l4 = *(const short4*)&lwT[(n0 + col) * 32 + 8 * g + 4 * h2];
#pragma unroll
      for (int r = 0; r < 4; ++r) {
        int reg = g * 4 + r;
        float ov = fmaxf(fmaf(pv[reg], 1.f / sums[reg], res[reg]), 0.f);
        short lv = (r == 0) ? l4.x : (r == 1) ? l4.y : (r == 2) ? l4.z : l4.w;
        p += ov * bf2f(lv);
      }
    }
  } else {
    __syncthreads();   // all waves done reading scr; scr union writable as yOut
#pragma unroll
    for (int reg = 0; reg < 16; ++reg) {
      int row = (reg & 3) + 8 * (reg >> 2) + 4 * h2;
      yOut[row * S_Y2 + n0 + col] =
          f2bf(fmaxf(fmaf(pv[reg], 1.f / sums[reg], res[reg]), 0.f));
    }
  }
  return p;
}

__global__ __launch_bounds__(256, 4) void autoint_main(
    const int* __restrict__ onehot_i, const float* __restrict__ onehot_x,
    const int* __restrict__ mh_i, const float* __restrict__ mh_x,
    const float* __restrict__ ctns, const float* __restrict__ xx,
    const float* __restrict__ xy,
    const float* __restrict__ bq1, const float* __restrict__ bk1,
    const float* __restrict__ bv1, const float* __restrict__ br1,
    const float* __restrict__ bq2, const float* __restrict__ bk2,
    const float* __restrict__ bv2, const float* __restrict__ br2,
    const float* __restrict__ logitb, const short* __restrict__ wbf,
    float* __restrict__ out) {
  // scr union (18432 B) hosts yA (layer inputs) + per-head tiles, lifetimes
  // fenced by barriers. wsh (32768 B) is the staged-weights buffer.
  __shared__ __align__(16) short scr[4][2][32 * S_T];
  __shared__ __align__(16) short wsh[16384];
  __shared__ float red[4];

  const int s = blockIdx.x;
  const int t = threadIdx.x;
  const int head = t >> 6;
  short* bQ = scr[head][0];
  short* bK = scr[head][1];
  short* yA = &scr[0][0][0];

  // ---- embedding build into yA [32][64] (bf16, 8B packed writes)
  for (int idx = t; idx < 320; idx += 256) {     // 20 onehot x 16 float4
    int f = idx >> 4, e4 = idx & 15;
    int row = onehot_i[s * 20 + f];
    float xw = onehot_x[s * 20 + f];
    float4 xv = *(const float4*)&xx[row * 64 + e4 * 4];
    uint2 w; w.x = pack2(xv.x * xw, xv.y * xw); w.y = pack2(xv.z * xw, xv.w * xw);
    *(uint2*)&yA[f * S_Y1 + e4 * 4] = w;
  }
  {                                               // 2 multihot x 16 float4, 8-way k-split
    int slot = t >> 3, ks = t & 7;
    int j = slot >> 4, e4 = slot & 15;
    const int* ip = &mh_i[(j * NSAMP + s) * 50];
    const float* xp = &mh_x[(j * NSAMP + s) * 50];
    float a0 = 0.f, a1 = 0.f, a2 = 0.f, a3 = 0.f;
    for (int k = ks; k < 50; k += 8) {
      float4 xv = *(const float4*)&xx[ip[k] * 64 + e4 * 4];
      float w = xp[k];
      a0 += xv.x * w; a1 += xv.y * w; a2 += xv.z * w; a3 += xv.w * w;
    }
#pragma unroll
    for (int d = 1; d < 8; d <<= 1) {
      a0 += __shfl_xor(a0, d); a1 += __shfl_xor(a1, d);
      a2 += __shfl_xor(a2, d); a3 += __shfl_xor(a3, d);
    }
    if (ks == 0) {
      uint2 w; w.x = pack2(a0, a1); w.y = pack2(a2, a3);
      *(uint2*)&yA[(20 + j) * S_Y1 + e4 * 4] = w;
    }
  }
  if (t < 160) {                                  // 10 ctns x 16 float4
    int ci = t >> 4, e4 = t & 15;
    float cv = ctns[s * 10 + ci];
    float4 xv = *(const float4*)&xy[ci * 64 + e4 * 4];
    uint2 w; w.x = pack2(cv * xv.x, cv * xv.y); w.y = pack2(cv * xv.z, cv * xv.w);
    *(uint2*)&yA[(22 + ci) * S_Y1 + e4 * 4] = w;
  }
  __syncthreads();

  attn_layer<64, S_Y1, false>(yA, yA,
      wbf + 0, wbf + 8192, wbf + 16384, wbf + 24576,
      bq1, bk1, bv1, br1, bQ, bK, wsh, nullptr);
  __syncthreads();   // yB (= yA region) fully written before layer2 frag load
  float p = attn_layer<128, S_Y2, true>(yA, nullptr,
      wbf + 32768, wbf + 49152, wbf + 65536, wbf + 81920,
      bq2, bk2, bv2, br2, bQ, bK, wsh, wbf + 98304);

  // ---- block reduce of logit partials, sigmoid
#pragma unroll
  for (int off = 32; off > 0; off >>= 1) p += __shfl_xor(p, off);
  if ((t & 63) == 0) red[head] = p;
  __syncthreads();
  if (t == 0) {
    float zz = red[0] + red[1] + red[2] + red[3] + logitb[0];
    out[s] = 1.f / (1.f + __expf(-zz));
  }
}

// fp32 -> bf16 weight conversion into ws:
// [0)QW1 [8192)KW1 [16384)VW1 [24576)RW1 [32768)QW2 [49152)KW2 [65536)VW2
// [81920)RW2 [98304)logitW TRANSPOSED [128][32]
__global__ void convert_w(const float* __restrict__ qw1, const float* __restrict__ kw1,
                          const float* __restrict__ vw1, const float* __restrict__ rw1,
                          const float* __restrict__ qw2, const float* __restrict__ kw2,
                          const float* __restrict__ vw2, const float* __restrict__ rw2,
                          const float* __restrict__ lw, short* __restrict__ outw) {
  int i = blockIdx.x * 256 + threadIdx.x;
  if (i >= 102400) return;
  float v;
  if (i < 32768) {
    int tsel = i >> 13, j = i & 8191;
    const float* src = tsel == 0 ? qw1 : tsel == 1 ? kw1 : tsel == 2 ? vw1 : rw1;
    v = src[j];
  } else if (i < 98304) {
    int k = i - 32768;
    int tsel = k >> 14, j = k & 16383;
    const float* src = tsel == 0 ? qw2 : tsel == 1 ? kw2 : tsel == 2 ? vw2 : rw2;
    v = src[j];
  } else {
    int j = i - 98304;                 // outw layout: lwT[col*32+row]
    v = lw[(j & 31) * 128 + (j >> 5)];
  }
  outw[i] = f2bf(v);
}

extern "C" void kernel_launch(void* const* d_in, const int* in_sizes, int n_in,
                              void* d_out, int out_size, void* d_ws, size_t ws_size,
                              hipStream_t stream) {
  short* wbf = (short*)d_ws;  // 204800 bytes used
  convert_w<<<400, 256, 0, stream>>>(
      (const float*)d_in[7], (const float*)d_in[9], (const float*)d_in[11],
      (const float*)d_in[13], (const float*)d_in[15], (const float*)d_in[17],
      (const float*)d_in[19], (const float*)d_in[21], (const float*)d_in[23], wbf);
  autoint_main<<<NSAMP, 256, 0, stream>>>(
      (const int*)d_in[0], (const float*)d_in[1], (const int*)d_in[2],
      (const float*)d_in[3], (const float*)d_in[4], (const float*)d_in[5],
      (const float*)d_in[6],
      (const float*)d_in[8], (const float*)d_in[10], (const float*)d_in[12],
      (const float*)d_in[14], (const float*)d_in[16], (const float*)d_in[18],
      (const float*)d_in[20], (const float*)d_in[22], (const float*)d_in[24],
      wbf, (float*)d_out);
}

// Round 11
// 381.087 us; speedup vs baseline: 1.0519x; 1.0519x over previous
//
#include <hip/hip_runtime.h>

// AutoInt fused: embedding gather -> 2x MHSA (32 fields, 4 heads x 32) -> logit.
// R11: 1024-thr blocks = 4 SAMPLES per block (grid 2048). wave w -> sample w&3,
//     head w>>2: the 4 same-head waves are barrier-aligned and issue IDENTICAL
//     W loads simultaneously -> L1 serves 3 of 4 (per-sample W traffic /4).
//     Per-sample math/LDS-overlay identical to R9 (32x32x16 MFMA, exp-sum
//     softmax via all-ones MFMA, fused logit).

#define NSAMP 8192
#define S_Y1 72    // layer1 input stride (shorts)
#define S_Y2 136   // layer2 input stride (shorts)
#define S_T 36     // 32x32 tile stride (shorts)

typedef __attribute__((ext_vector_type(8))) short bf8_t;   // 8 bf16 (4 VGPRs)
typedef __attribute__((ext_vector_type(16))) float f16v;   // 32x32 C/D

__device__ __forceinline__ short f2bf(float f) {
  unsigned u = __float_as_uint(f);
  u += 0x7fffu + ((u >> 16) & 1u);   // RNE
  return (short)(u >> 16);
}
__device__ __forceinline__ unsigned pack2(float a, float b) {
  return ((unsigned)(unsigned short)f2bf(a)) |
         (((unsigned)(unsigned short)f2bf(b)) << 16);
}
__device__ __forceinline__ float bf2f(short s) {
  return __uint_as_float(((unsigned)(unsigned short)s) << 16);
}
__device__ __forceinline__ f16v mfma32(bf8_t a, bf8_t b, f16v c) {
  return __builtin_amdgcn_mfma_f32_32x32x16_bf16(a, b, c, 0, 0, 0);
}

// C = y(32xD) * W(32xD)^T + bias : one 32x32 tile per wave.
template<int D_IN>
__device__ __forceinline__ f16v proj32(const bf8_t (&af)[D_IN / 16],
                                       const short* __restrict__ W,
                                       const float* __restrict__ bias,
                                       int n0, int col, int h2) {
  float bb = bias[n0 + col];
  f16v acc;
#pragma unroll
  for (int i = 0; i < 16; ++i) acc[i] = bb;
#pragma unroll
  for (int kc = 0; kc < D_IN / 16; ++kc) {
    bf8_t b = *(const bf8_t*)&W[(n0 + col) * D_IN + kc * 16 + h2 * 8];
    acc = mfma32(af[kc], b, acc);
  }
  return acc;
}

// One attention layer for this wave's (sample, head). Barriers are block-wide
// and phase-aligned across all 16 waves (the W-sharing mechanism).
template<int D_IN, int S_IN, bool FUSE>
__device__ float attn_layer(const short* yIn, short* yOut,
                            const short* __restrict__ Wq, const short* __restrict__ Wk,
                            const short* __restrict__ Wv, const short* __restrict__ Wr,
                            const float* __restrict__ bq, const float* __restrict__ bk,
                            const float* __restrict__ bvp, const float* __restrict__ br,
                            short* bQ, short* bK, const short* __restrict__ lwT,
                            int n0, int col, int h2) {
  constexpr int KS = D_IN / 16;

  // A-fragments of this sample's yIn
  bf8_t af[KS];
#pragma unroll
  for (int kc = 0; kc < KS; ++kc)
    af[kc] = *(const bf8_t*)&yIn[col * S_IN + kc * 16 + h2 * 8];
  __syncthreads();   // all samples' yIn read; tile regions writable

  // ---- Q -> bQ row-major
  {
    f16v q = proj32<D_IN>(af, Wq, bq, n0, col, h2);
#pragma unroll
    for (int reg = 0; reg < 16; ++reg) {
      int row = (reg & 3) + 8 * (reg >> 2) + 4 * h2;
      bQ[row * S_T + col] = f2bf(q[reg]);
    }
  }
  // ---- K -> bK row-major
  {
    f16v k = proj32<D_IN>(af, Wk, bk, n0, col, h2);
#pragma unroll
    for (int reg = 0; reg < 16; ++reg) {
      int row = (reg & 3) + 8 * (reg >> 2) + 4 * h2;
      bK[row * S_T + col] = f2bf(k[reg]);
    }
  }
  // ---- Res -> registers (C-layout, aligned with PV output)
  f16v res = proj32<D_IN>(af, Wr, br, n0, col, h2);

  // ---- scores = Q K^T (K-dim = 32 head dims -> 2 chunks)
  f16v z;
#pragma unroll
  for (int i = 0; i < 16; ++i) z[i] = 0.f;
#pragma unroll
  for (int kc = 0; kc < 2; ++kc) {
    bf8_t qa = *(const bf8_t*)&bQ[col * S_T + kc * 16 + h2 * 8];
    bf8_t kb = *(const bf8_t*)&bK[col * S_T + kc * 16 + h2 * 8];
    z = mfma32(qa, kb, z);
  }

  // ---- e = exp(z) unnormalized -> bQ (scores O(1), no max-sub needed)
#pragma unroll
  for (int reg = 0; reg < 16; ++reg) {
    int row = (reg & 3) + 8 * (reg >> 2) + 4 * h2;
    bQ[row * S_T + col] = f2bf(__expf(z[reg]));
  }

  // ---- V -> bK transposed: bK[i=col][f=row], packed short4 runs
  {
    f16v v = proj32<D_IN>(af, Wv, bvp, n0, col, h2);
#pragma unroll
    for (int g = 0; g < 4; ++g) {
      short4 pk;
      pk.x = f2bf(v[g * 4 + 0]); pk.y = f2bf(v[g * 4 + 1]);
      pk.z = f2bf(v[g * 4 + 2]); pk.w = f2bf(v[g * 4 + 3]);
      *(short4*)&bK[col * S_T + 8 * g + 4 * h2] = pk;
    }
  }

  // ---- PV (unnormalized) + row-sums via all-ones B-frag
  const short onebf = (short)0x3F80;
  bf8_t ones = {onebf, onebf, onebf, onebf, onebf, onebf, onebf, onebf};
  f16v pv, sums;
#pragma unroll
  for (int i = 0; i < 16; ++i) { pv[i] = 0.f; sums[i] = 0.f; }
#pragma unroll
  for (int kc = 0; kc < 2; ++kc) {
    bf8_t pa = *(const bf8_t*)&bQ[col * S_T + kc * 16 + h2 * 8];
    bf8_t vb = *(const bf8_t*)&bK[col * S_T + kc * 16 + h2 * 8];
    pv = mfma32(pa, vb, pv);
    sums = mfma32(pa, ones, sums);
  }

  // ---- O = PV/s + Res, relu; store (layer1) or fuse logit dot (layer2)
  float p = 0.f;
  if (FUSE) {
#pragma unroll
    for (int g = 0; g < 4; ++g) {
      short4 l4 = *(const short4*)&lwT[(n0 + col) * 32 + 8 * g + 4 * h2];
#pragma unroll
      for (int r = 0; r < 4; ++r) {
        int reg = g * 4 + r;
        float ov = fmaxf(fmaf(pv[reg], 1.f / sums[reg], res[reg]), 0.f);
        short lv = (r == 0) ? l4.x : (r == 1) ? l4.y : (r == 2) ? l4.z : l4.w;
        p += ov * bf2f(lv);
      }
    }
  } else {
    __syncthreads();   // all waves done reading tiles; regions writable as yOut
#pragma unroll
    for (int reg = 0; reg < 16; ++reg) {
      int row = (reg & 3) + 8 * (reg >> 2) + 4 * h2;
      yOut[row * S_Y2 + n0 + col] =
          f2bf(fmaxf(fmaf(pv[reg], 1.f / sums[reg], res[reg]), 0.f));
    }
  }
  return p;
}

__global__ __launch_bounds__(1024, 4) void autoint_main(
    const int* __restrict__ onehot_i, const float* __restrict__ onehot_x,
    const int* __restrict__ mh_i, const float* __restrict__ mh_x,
    const float* __restrict__ ctns, const float* __restrict__ xx,
    const float* __restrict__ xy,
    const float* __restrict__ bq1, const float* __restrict__ bk1,
    const float* __restrict__ bv1, const float* __restrict__ br1,
    const float* __restrict__ bq2, const float* __restrict__ bk2,
    const float* __restrict__ bv2, const float* __restrict__ br2,
    const float* __restrict__ logitb, const short* __restrict__ wbf,
    float* __restrict__ out) {
  // Per-sample 18432B region: 4 heads x (bQ,bK) tiles; yA (4608B) and
  // yB (8704B) overlay its base, lifetimes fenced by the block barriers.
  __shared__ __align__(16) short scr[4][9216];
  __shared__ float red[16];

  const int t = threadIdx.x;
  const int wave = t >> 6;
  const int lane = t & 63;
  const int sm = wave & 3;            // sample within block
  const int head = wave >> 2;         // 4 waves share a head -> same W addrs
  const int col = lane & 31;
  const int h2 = lane >> 5;
  const int n0 = head * 32;
  const int s = blockIdx.x * 4 + sm;

  short* bQ = &scr[sm][(head * 2 + 0) * 1152];
  short* bK = &scr[sm][(head * 2 + 1) * 1152];
  short* yS = &scr[sm][0];            // yA/yB overlay base for this sample

  // ---- embedding: thread quarter q builds sample q's yA [32][64]
  {
    const int se = t >> 8;             // sample index for embed work
    const int tt = t & 255;
    const int sg = blockIdx.x * 4 + se;
    short* yA = &scr[se][0];
    for (int idx = tt; idx < 320; idx += 256) {    // 20 onehot x 16 float4
      int f = idx >> 4, e4 = idx & 15;
      int row = onehot_i[sg * 20 + f];
      float xw = onehot_x[sg * 20 + f];
      float4 xv = *(const float4*)&xx[row * 64 + e4 * 4];
      uint2 w; w.x = pack2(xv.x * xw, xv.y * xw); w.y = pack2(xv.z * xw, xv.w * xw);
      *(uint2*)&yA[f * S_Y1 + e4 * 4] = w;
    }
    {                                              // 2 multihot x 16 float4, 8-way k-split
      int slot = tt >> 3, ks = tt & 7;
      int j = slot >> 4, e4 = slot & 15;
      const int* ip = &mh_i[(j * NSAMP + sg) * 50];
      const float* xp = &mh_x[(j * NSAMP + sg) * 50];
      float a0 = 0.f, a1 = 0.f, a2 = 0.f, a3 = 0.f;
      for (int k = ks; k < 50; k += 8) {
        float4 xv = *(const float4*)&xx[ip[k] * 64 + e4 * 4];
        float w = xp[k];
        a0 += xv.x * w; a1 += xv.y * w; a2 += xv.z * w; a3 += xv.w * w;
      }
#pragma unroll
      for (int d = 1; d < 8; d <<= 1) {
        a0 += __shfl_xor(a0, d); a1 += __shfl_xor(a1, d);
        a2 += __shfl_xor(a2, d); a3 += __shfl_xor(a3, d);
      }
      if (ks == 0) {
        uint2 w; w.x = pack2(a0, a1); w.y = pack2(a2, a3);
        *(uint2*)&yA[(20 + j) * S_Y1 + e4 * 4] = w;
      }
    }
    if (tt < 160) {                                // 10 ctns x 16 float4
      int ci = tt >> 4, e4 = tt & 15;
      float cv = ctns[sg * 10 + ci];
      float4 xv = *(const float4*)&xy[ci * 64 + e4 * 4];
      uint2 w; w.x = pack2(cv * xv.x, cv * xv.y); w.y = pack2(cv * xv.z, cv * xv.w);
      *(uint2*)&yA[(22 + ci) * S_Y1 + e4 * 4] = w;
    }
  }
  __syncthreads();

  attn_layer<64, S_Y1, false>(yS, yS,
      wbf + 0, wbf + 8192, wbf + 16384, wbf + 24576,
      bq1, bk1, bv1, br1, bQ, bK, nullptr, n0, col, h2);
  __syncthreads();   // yB fully written before layer2 frag load
  float p = attn_layer<128, S_Y2, true>(yS, nullptr,
      wbf + 32768, wbf + 49152, wbf + 65536, wbf + 81920,
      bq2, bk2, bv2, br2, bQ, bK, wbf + 98304, n0, col, h2);

  // ---- logit partials: wave-reduce, then per-sample combine
#pragma unroll
  for (int off = 32; off > 0; off >>= 1) p += __shfl_xor(p, off);
  if (lane == 0) red[wave] = p;
  __syncthreads();
  if (t < 4) {
    float zz = red[t] + red[4 + t] + red[8 + t] + red[12 + t] + logitb[0];
    out[blockIdx.x * 4 + t] = 1.f / (1.f + __expf(-zz));
  }
}

// fp32 -> bf16 weight conversion into ws:
// [0)QW1 [8192)KW1 [16384)VW1 [24576)RW1 [32768)QW2 [49152)KW2 [65536)VW2
// [81920)RW2 [98304)logitW TRANSPOSED [128][32]
__global__ void convert_w(const float* __restrict__ qw1, const float* __restrict__ kw1,
                          const float* __restrict__ vw1, const float* __restrict__ rw1,
                          const float* __restrict__ qw2, const float* __restrict__ kw2,
                          const float* __restrict__ vw2, const float* __restrict__ rw2,
                          const float* __restrict__ lw, short* __restrict__ outw) {
  int i = blockIdx.x * 256 + threadIdx.x;
  if (i >= 102400) return;
  float v;
  if (i < 32768) {
    int tsel = i >> 13, j = i & 8191;
    const float* src = tsel == 0 ? qw1 : tsel == 1 ? kw1 : tsel == 2 ? vw1 : rw1;
    v = src[j];
  } else if (i < 98304) {
    int k = i - 32768;
    int tsel = k >> 14, j = k & 16383;
    const float* src = tsel == 0 ? qw2 : tsel == 1 ? kw2 : tsel == 2 ? vw2 : rw2;
    v = src[j];
  } else {
    int j = i - 98304;                 // outw layout: lwT[col*32+row]
    v = lw[(j & 31) * 128 + (j >> 5)];
  }
  outw[i] = f2bf(v);
}

extern "C" void kernel_launch(void* const* d_in, const int* in_sizes, int n_in,
                              void* d_out, int out_size, void* d_ws, size_t ws_size,
                              hipStream_t stream) {
  short* wbf = (short*)d_ws;  // 204800 bytes used
  convert_w<<<400, 256, 0, stream>>>(
      (const float*)d_in[7], (const float*)d_in[9], (const float*)d_in[11],
      (const float*)d_in[13], (const float*)d_in[15], (const float*)d_in[17],
      (const float*)d_in[19], (const float*)d_in[21], (const float*)d_in[23], wbf);
  autoint_main<<<NSAMP / 4, 1024, 0, stream>>>(
      (const int*)d_in[0], (const float*)d_in[1], (const int*)d_in[2],
      (const float*)d_in[3], (const float*)d_in[4], (const float*)d_in[5],
      (const float*)d_in[6],
      (const float*)d_in[8], (const float*)d_in[10], (const float*)d_in[12],
      (const float*)d_in[14], (const float*)d_in[16], (const float*)d_in[18],
      (const float*)d_in[20], (const float*)d_in[22], (const float*)d_in[24],
      wbf, (float*)d_out);
}

// Round 12
// 304.333 us; speedup vs baseline: 1.3172x; 1.2522x over previous
//
#include <hip/hip_runtime.h>

// AutoInt fused: embedding gather -> 2x MHSA (32 fields, 4 heads x 32) -> logit.
// R12: 2 SAMPLES PER WAVE. Block (256 thr) = 2 samples; wave = head, handles
//     both samples. Per projection W-fragments load ONCE per wave and feed two
//     independent MFMA chains -> wave count halves, per-sample W loads halve,
//     chains overlap. R9 math (32x32x16 MFMA, exp-sum softmax, fused logit).

#define NSAMP 8192
#define S_Y1 72    // layer1 input stride (shorts)
#define S_Y2 136   // layer2 input stride (shorts)
#define S_T 36     // 32x32 tile stride (shorts)

typedef __attribute__((ext_vector_type(8))) short bf8_t;   // 8 bf16 (4 VGPRs)
typedef __attribute__((ext_vector_type(16))) float f16v;   // 32x32 C/D

__device__ __forceinline__ short f2bf(float f) {
  unsigned u = __float_as_uint(f);
  u += 0x7fffu + ((u >> 16) & 1u);   // RNE
  return (short)(u >> 16);
}
__device__ __forceinline__ unsigned pack2(float a, float b) {
  return ((unsigned)(unsigned short)f2bf(a)) |
         (((unsigned)(unsigned short)f2bf(b)) << 16);
}
__device__ __forceinline__ float bf2f(short s) {
  return __uint_as_float(((unsigned)(unsigned short)s) << 16);
}
__device__ __forceinline__ f16v mfma32(bf8_t a, bf8_t b, f16v c) {
  return __builtin_amdgcn_mfma_f32_32x32x16_bf16(a, b, c, 0, 0, 0);
}

// Two samples' 32x32 proj tiles sharing one set of W fragments.
template<int D>
__device__ __forceinline__ void proj2(const bf8_t (&af)[2][D / 16],
                                      const short* __restrict__ W,
                                      const float* __restrict__ bias,
                                      int n0, int col, int h2, f16v (&o)[2]) {
  float bb = bias[n0 + col];
#pragma unroll
  for (int i = 0; i < 16; ++i) { o[0][i] = bb; o[1][i] = bb; }
#pragma unroll
  for (int kc = 0; kc < D / 16; ++kc) {
    bf8_t w = *(const bf8_t*)&W[(n0 + col) * D + kc * 16 + h2 * 8];
    o[0] = mfma32(af[0][kc], w, o[0]);
    o[1] = mfma32(af[1][kc], w, o[1]);
  }
}

// One attention layer for this wave's head, BOTH samples.
// bQ[sp]/bK[sp] are per-(sample,head) tiles; yIn/yOut overlay tile regions,
// lifetimes fenced by barriers (R9 pattern, doubled).
template<int D_IN, int S_IN, bool FUSE>
__device__ void attn_layer(const short* yIn0, const short* yIn1,
                           short* yOut0, short* yOut1,
                           const short* __restrict__ Wq, const short* __restrict__ Wk,
                           const short* __restrict__ Wv, const short* __restrict__ Wr,
                           const float* __restrict__ bq, const float* __restrict__ bk,
                           const float* __restrict__ bvp, const float* __restrict__ br,
                           short* bQ0, short* bK0, short* bQ1, short* bK1,
                           const short* __restrict__ lwT,
                           int n0, int col, int h2, float (&pp)[2]) {
  constexpr int KS = D_IN / 16;
  const short* yIn[2] = {yIn0, yIn1};
  short* bQ[2] = {bQ0, bQ1};
  short* bK[2] = {bK0, bK1};

  // A-fragments for both samples
  bf8_t af[2][KS];
#pragma unroll
  for (int sp = 0; sp < 2; ++sp)
#pragma unroll
    for (int kc = 0; kc < KS; ++kc)
      af[sp][kc] = *(const bf8_t*)&yIn[sp][col * S_IN + kc * 16 + h2 * 8];
  __syncthreads();   // yIn overlays dead; tile regions writable

  f16v acc[2];

  // ---- Q -> bQ row-major (both samples)
  proj2<D_IN>(af, Wq, bq, n0, col, h2, acc);
#pragma unroll
  for (int sp = 0; sp < 2; ++sp)
#pragma unroll
    for (int reg = 0; reg < 16; ++reg) {
      int row = (reg & 3) + 8 * (reg >> 2) + 4 * h2;
      bQ[sp][row * S_T + col] = f2bf(acc[sp][reg]);
    }

  // ---- K -> bK row-major
  proj2<D_IN>(af, Wk, bk, n0, col, h2, acc);
#pragma unroll
  for (int sp = 0; sp < 2; ++sp)
#pragma unroll
    for (int reg = 0; reg < 16; ++reg) {
      int row = (reg & 3) + 8 * (reg >> 2) + 4 * h2;
      bK[sp][row * S_T + col] = f2bf(acc[sp][reg]);
    }

  // ---- Res -> registers (C-layout, aligned with PV output)
  f16v res[2];
  proj2<D_IN>(af, Wr, br, n0, col, h2, res);

  // ---- scores = Q K^T; e = exp(z) -> bQ (unnormalized, scores O(1))
#pragma unroll
  for (int sp = 0; sp < 2; ++sp) {
    f16v z;
#pragma unroll
    for (int i = 0; i < 16; ++i) z[i] = 0.f;
#pragma unroll
    for (int kc = 0; kc < 2; ++kc) {
      bf8_t qa = *(const bf8_t*)&bQ[sp][col * S_T + kc * 16 + h2 * 8];
      bf8_t kb = *(const bf8_t*)&bK[sp][col * S_T + kc * 16 + h2 * 8];
      z = mfma32(qa, kb, z);
    }
#pragma unroll
    for (int reg = 0; reg < 16; ++reg) {
      int row = (reg & 3) + 8 * (reg >> 2) + 4 * h2;
      bQ[sp][row * S_T + col] = f2bf(__expf(z[reg]));
    }
  }

  // ---- V -> bK transposed (both samples)
  proj2<D_IN>(af, Wv, bvp, n0, col, h2, acc);
#pragma unroll
  for (int sp = 0; sp < 2; ++sp)
#pragma unroll
    for (int g = 0; g < 4; ++g) {
      short4 pk;
      pk.x = f2bf(acc[sp][g * 4 + 0]); pk.y = f2bf(acc[sp][g * 4 + 1]);
      pk.z = f2bf(acc[sp][g * 4 + 2]); pk.w = f2bf(acc[sp][g * 4 + 3]);
      *(short4*)&bK[sp][col * S_T + 8 * g + 4 * h2] = pk;
    }

  // ---- PV + row-sums (all-ones B-frag), then epilogue per sample
  const short onebf = (short)0x3F80;
  bf8_t ones = {onebf, onebf, onebf, onebf, onebf, onebf, onebf, onebf};
  f16v pv[2], sums[2];
#pragma unroll
  for (int sp = 0; sp < 2; ++sp) {
#pragma unroll
    for (int i = 0; i < 16; ++i) { pv[sp][i] = 0.f; sums[sp][i] = 0.f; }
#pragma unroll
    for (int kc = 0; kc < 2; ++kc) {
      bf8_t pa = *(const bf8_t*)&bQ[sp][col * S_T + kc * 16 + h2 * 8];
      bf8_t vb = *(const bf8_t*)&bK[sp][col * S_T + kc * 16 + h2 * 8];
      pv[sp] = mfma32(pa, vb, pv[sp]);
      sums[sp] = mfma32(pa, ones, sums[sp]);
    }
  }

  if (FUSE) {
#pragma unroll
    for (int g = 0; g < 4; ++g) {
      short4 l4 = *(const short4*)&lwT[(n0 + col) * 32 + 8 * g + 4 * h2];
#pragma unroll
      for (int r = 0; r < 4; ++r) {
        int reg = g * 4 + r;
        float lw = bf2f((r == 0) ? l4.x : (r == 1) ? l4.y : (r == 2) ? l4.z : l4.w);
        pp[0] += fmaxf(fmaf(pv[0][reg], 1.f / sums[0][reg], res[0][reg]), 0.f) * lw;
        pp[1] += fmaxf(fmaf(pv[1][reg], 1.f / sums[1][reg], res[1][reg]), 0.f) * lw;
      }
    }
  } else {
    __syncthreads();   // all waves done reading tiles; regions writable as yOut
    short* yOut[2] = {yOut0, yOut1};
#pragma unroll
    for (int sp = 0; sp < 2; ++sp)
#pragma unroll
      for (int reg = 0; reg < 16; ++reg) {
        int row = (reg & 3) + 8 * (reg >> 2) + 4 * h2;
        yOut[sp][row * S_Y2 + n0 + col] =
            f2bf(fmaxf(fmaf(pv[sp][reg], 1.f / sums[sp][reg], res[sp][reg]), 0.f));
      }
  }
}

__global__ __launch_bounds__(256, 3) void autoint_main(
    const int* __restrict__ onehot_i, const float* __restrict__ onehot_x,
    const int* __restrict__ mh_i, const float* __restrict__ mh_x,
    const float* __restrict__ ctns, const float* __restrict__ xx,
    const float* __restrict__ xy,
    const float* __restrict__ bq1, const float* __restrict__ bk1,
    const float* __restrict__ bv1, const float* __restrict__ br1,
    const float* __restrict__ bq2, const float* __restrict__ bk2,
    const float* __restrict__ bv2, const float* __restrict__ br2,
    const float* __restrict__ logitb, const short* __restrict__ wbf,
    float* __restrict__ out) {
  // Per-sample 18432B region (8 head-tiles) hosting y1 (4608B) / y2 (8704B)
  // overlays at its base, lifetimes fenced by barriers. Two samples/block.
  __shared__ __align__(16) short scr[2][9216];
  __shared__ float red[4][2];

  const int t = threadIdx.x;
  const int head = t >> 6;
  const int lane = t & 63;
  const int col = lane & 31;
  const int h2 = lane >> 5;
  const int n0 = head * 32;
  const int s0 = blockIdx.x * 2;

  short* bQ0 = &scr[0][(head * 2 + 0) * 1152];
  short* bK0 = &scr[0][(head * 2 + 1) * 1152];
  short* bQ1 = &scr[1][(head * 2 + 0) * 1152];
  short* bK1 = &scr[1][(head * 2 + 1) * 1152];

  // ---- embedding build: both samples' y1, all 256 threads each
#pragma unroll
  for (int se = 0; se < 2; ++se) {
    const int sg = s0 + se;
    short* yA = &scr[se][0];
    for (int idx = t; idx < 320; idx += 256) {     // 20 onehot x 16 float4
      int f = idx >> 4, e4 = idx & 15;
      int row = onehot_i[sg * 20 + f];
      float xw = onehot_x[sg * 20 + f];
      float4 xv = *(const float4*)&xx[row * 64 + e4 * 4];
      uint2 w; w.x = pack2(xv.x * xw, xv.y * xw); w.y = pack2(xv.z * xw, xv.w * xw);
      *(uint2*)&yA[f * S_Y1 + e4 * 4] = w;
    }
    {                                               // 2 multihot x 16 float4, 8-way k-split
      int slot = t >> 3, ks = t & 7;
      int j = slot >> 4, e4 = slot & 15;
      const int* ip = &mh_i[(j * NSAMP + sg) * 50];
      const float* xp = &mh_x[(j * NSAMP + sg) * 50];
      float a0 = 0.f, a1 = 0.f, a2 = 0.f, a3 = 0.f;
      for (int k = ks; k < 50; k += 8) {
        float4 xv = *(const float4*)&xx[ip[k] * 64 + e4 * 4];
        float w = xp[k];
        a0 += xv.x * w; a1 += xv.y * w; a2 += xv.z * w; a3 += xv.w * w;
      }
#pragma unroll
      for (int d = 1; d < 8; d <<= 1) {
        a0 += __shfl_xor(a0, d); a1 += __shfl_xor(a1, d);
        a2 += __shfl_xor(a2, d); a3 += __shfl_xor(a3, d);
      }
      if (ks == 0) {
        uint2 w; w.x = pack2(a0, a1); w.y = pack2(a2, a3);
        *(uint2*)&yA[(20 + j) * S_Y1 + e4 * 4] = w;
      }
    }
    if (t < 160) {                                  // 10 ctns x 16 float4
      int ci = t >> 4, e4 = t & 15;
      float cv = ctns[sg * 10 + ci];
      float4 xv = *(const float4*)&xy[ci * 64 + e4 * 4];
      uint2 w; w.x = pack2(cv * xv.x, cv * xv.y); w.y = pack2(cv * xv.z, cv * xv.w);
      *(uint2*)&yA[(22 + ci) * S_Y1 + e4 * 4] = w;
    }
  }
  __syncthreads();

  float pp[2] = {0.f, 0.f};
  attn_layer<64, S_Y1, false>(&scr[0][0], &scr[1][0], &scr[0][0], &scr[1][0],
      wbf + 0, wbf + 8192, wbf + 16384, wbf + 24576,
      bq1, bk1, bv1, br1, bQ0, bK0, bQ1, bK1, nullptr, n0, col, h2, pp);
  __syncthreads();   // y2 fully written before layer2 frag load
  attn_layer<128, S_Y2, true>(&scr[0][0], &scr[1][0], nullptr, nullptr,
      wbf + 32768, wbf + 49152, wbf + 65536, wbf + 81920,
      bq2, bk2, bv2, br2, bQ0, bK0, bQ1, bK1, wbf + 98304, n0, col, h2, pp);

  // ---- logit partials: wave-reduce each sample, combine heads
#pragma unroll
  for (int off = 32; off > 0; off >>= 1) {
    pp[0] += __shfl_xor(pp[0], off);
    pp[1] += __shfl_xor(pp[1], off);
  }
  if (lane == 0) { red[head][0] = pp[0]; red[head][1] = pp[1]; }
  __syncthreads();
  if (t < 2) {
    float zz = red[0][t] + red[1][t] + red[2][t] + red[3][t] + logitb[0];
    out[s0 + t] = 1.f / (1.f + __expf(-zz));
  }
}

// fp32 -> bf16 weight conversion into ws:
// [0)QW1 [8192)KW1 [16384)VW1 [24576)RW1 [32768)QW2 [49152)KW2 [65536)VW2
// [81920)RW2 [98304)logitW TRANSPOSED [128][32]
__global__ void convert_w(const float* __restrict__ qw1, const float* __restrict__ kw1,
                          const float* __restrict__ vw1, const float* __restrict__ rw1,
                          const float* __restrict__ qw2, const float* __restrict__ kw2,
                          const float* __restrict__ vw2, const float* __restrict__ rw2,
                          const float* __restrict__ lw, short* __restrict__ outw) {
  int i = blockIdx.x * 256 + threadIdx.x;
  if (i >= 102400) return;
  float v;
  if (i < 32768) {
    int tsel = i >> 13, j = i & 8191;
    const float* src = tsel == 0 ? qw1 : tsel == 1 ? kw1 : tsel == 2 ? vw1 : rw1;
    v = src[j];
  } else if (i < 98304) {
    int k = i - 32768;
    int tsel = k >> 14, j = k & 16383;
    const float* src = tsel == 0 ? qw2 : tsel == 1 ? kw2 : tsel == 2 ? vw2 : rw2;
    v = src[j];
  } else {
    int j = i - 98304;                 // outw layout: lwT[col*32+row]
    v = lw[(j & 31) * 128 + (j >> 5)];
  }
  outw[i] = f2bf(v);
}

extern "C" void kernel_launch(void* const* d_in, const int* in_sizes, int n_in,
                              void* d_out, int out_size, void* d_ws, size_t ws_size,
                              hipStream_t stream) {
  short* wbf = (short*)d_ws;  // 204800 bytes used
  convert_w<<<400, 256, 0, stream>>>(
      (const float*)d_in[7], (const float*)d_in[9], (const float*)d_in[11],
      (const float*)d_in[13], (const float*)d_in[15], (const float*)d_in[17],
      (const float*)d_in[19], (const float*)d_in[21], (const float*)d_in[23], wbf);
  autoint_main<<<NSAMP / 2, 256, 0, stream>>>(
      (const int*)d_in[0], (const float*)d_in[1], (const int*)d_in[2],
      (const float*)d_in[3], (const float*)d_in[4], (const float*)d_in[5],
      (const float*)d_in[6],
      (const float*)d_in[8], (const float*)d_in[10], (const float*)d_in[12],
      (const float*)d_in[14], (const float*)d_in[16], (const float*)d_in[18],
      (const float*)d_in[20], (const float*)d_in[22], (const float*)d_in[24],
      wbf, (float*)d_out);
}